// Round 3
// baseline (524.037 us; speedup 1.0000x reference)
//
#include <hip/hip_runtime.h>
#include <hip/hip_bf16.h>

// Shapes (fixed by reference): B=32, N=12, S=512, D=256, A=96
#define B_ 32
#define N_ 12
#define S_ 512
#define D_ 256
#define A_ 96

typedef __attribute__((ext_vector_type(8))) short short8;   // 8 bf16 (4 VGPRs)
typedef __attribute__((ext_vector_type(4))) float float4v;  // MFMA acc

typedef const __attribute__((address_space(1))) void* gas_cvp;
typedef __attribute__((address_space(3))) void* las_vp;

static __device__ __forceinline__ void gl_lds16(const ushort* g, ushort* l) {
  __builtin_amdgcn_global_load_lds((gas_cvp)g, (las_vp)l, 16, 0, 0);
}

// fp32 -> bf16 round-to-nearest-even (data has no NaN/Inf)
static __device__ __forceinline__ ushort f2bf(float f) {
  union { float f; unsigned u; } a;
  a.f = f;
  return (ushort)((a.u + 0x7FFFu + ((a.u >> 16) & 1u)) >> 16);
}

// ---------------------------------------------------------------------------
// Kernel 1: qk = emb @ Wqk + bqk  [N,S,D] fp32 (for kernel 2), and
//           q = softmax(qk, d) written bf16 [n][s][d].
// ---------------------------------------------------------------------------
__global__ __launch_bounds__(256) void k_qk_softmax_q(
    const float* __restrict__ emb, const float* __restrict__ Wqk,
    const float* __restrict__ bqk, float* __restrict__ qk,
    ushort* __restrict__ qb) {
  int ns = blockIdx.x;
  int d = threadIdx.x;
  __shared__ float se[A_];
  __shared__ float red[8];
  if (d < A_) se[d] = emb[ns * A_ + d];
  __syncthreads();
  float acc = bqk[d];
#pragma unroll
  for (int a = 0; a < A_; ++a) acc = fmaf(se[a], Wqk[a * D_ + d], acc);
  qk[ns * D_ + d] = acc;
  float m = acc;
  for (int off = 32; off; off >>= 1) m = fmaxf(m, __shfl_xor(m, off));
  if ((d & 63) == 0) red[d >> 6] = m;
  __syncthreads();
  m = fmaxf(fmaxf(red[0], red[1]), fmaxf(red[2], red[3]));
  float e = __expf(acc - m);
  float sum = e;
  for (int off = 32; off; off >>= 1) sum += __shfl_xor(sum, off);
  if ((d & 63) == 0) red[4 + (d >> 6)] = sum;
  __syncthreads();
  sum = red[4] + red[5] + red[6] + red[7];
  qb[ns * D_ + d] = f2bf(e / sum);
}

// ---------------------------------------------------------------------------
// Kernel 2: kT[n][d][s] = softmax over s of qk[n][s][d], bf16 output.
// ---------------------------------------------------------------------------
__global__ __launch_bounds__(256) void k_softmax_kT(
    const float* __restrict__ qk, ushort* __restrict__ kTb) {
  int d = blockIdx.x;
  int n = blockIdx.y;
  int s = threadIdx.x;
  __shared__ float red[8];
  float v0 = qk[(n * S_ + s) * D_ + d];
  float v1 = qk[(n * S_ + s + 256) * D_ + d];
  float m = fmaxf(v0, v1);
  for (int off = 32; off; off >>= 1) m = fmaxf(m, __shfl_xor(m, off));
  if ((s & 63) == 0) red[s >> 6] = m;
  __syncthreads();
  m = fmaxf(fmaxf(red[0], red[1]), fmaxf(red[2], red[3]));
  float e0 = __expf(v0 - m), e1 = __expf(v1 - m);
  float sum = e0 + e1;
  for (int off = 32; off; off >>= 1) sum += __shfl_xor(sum, off);
  if ((s & 63) == 0) red[4 + (s >> 6)] = sum;
  __syncthreads();
  sum = red[4] + red[5] + red[6] + red[7];
  float inv = 1.0f / sum;
  kTb[(n * D_ + d) * S_ + s] = f2bf(e0 * inv);
  kTb[(n * D_ + d) * S_ + s + 256] = f2bf(e1 * inv);
}

// ---------------------------------------------------------------------------
// Kernel 3: WvT[c][e] = bf16(Wv[e][c])  (tiny: 256x256)
// ---------------------------------------------------------------------------
__global__ __launch_bounds__(256) void k_wvt(const float* __restrict__ Wv,
                                             ushort* __restrict__ WvT) {
  int c = blockIdx.x, e = threadIdx.x;
  WvT[c * D_ + e] = f2bf(Wv[e * D_ + c]);
}

// ---------------------------------------------------------------------------
// Kernel 4: vTb[bn][e][s] = bf16(value[bn][s][e])  (64x64 LDS-tile transpose)
// Coalesced float4 reads, coalesced 16B writes.
// ---------------------------------------------------------------------------
__global__ __launch_bounds__(256) void k_vT(const float* __restrict__ value,
                                            ushort* __restrict__ vTb) {
  const int s0 = blockIdx.x * 64;
  const int e0 = blockIdx.y * 64;
  const size_t bz = blockIdx.z;
  __shared__ ushort lds[64 * 72];  // row stride 144B (16B-aligned)
  const float* vb = value + bz * (size_t)(S_ * D_);
  const int tid = threadIdx.x;
#pragma unroll
  for (int t = 0; t < 4; ++t) {
    int id = t * 256 + tid;
    int r = id >> 4;    // s-local 0..63
    int c4 = id & 15;   // float4 index along e
    float4 f = *(const float4*)(vb + (size_t)(s0 + r) * D_ + e0 + c4 * 4);
    lds[(c4 * 4 + 0) * 72 + r] = f2bf(f.x);
    lds[(c4 * 4 + 1) * 72 + r] = f2bf(f.y);
    lds[(c4 * 4 + 2) * 72 + r] = f2bf(f.z);
    lds[(c4 * 4 + 3) * 72 + r] = f2bf(f.w);
  }
  __syncthreads();
  ushort* ob = vTb + bz * (size_t)(D_ * S_);
#pragma unroll
  for (int t = 0; t < 2; ++t) {
    int id = t * 256 + tid;
    int e = id >> 3;    // 0..63
    int c8 = id & 7;    // ushort8 index along s
    *(uint4*)(ob + (size_t)(e0 + e) * S_ + s0 + c8 * 8) =
        *(const uint4*)(&lds[e * 72 + c8 * 8]);
  }
}

// ---------------------------------------------------------------------------
// Shared NT-GEMM core: C[128x128] += A[128xK] * B[128xK]^T, bf16 MFMA,
// BK=64, global_load_lds 16B staging, unpadded LDS (m97 structure).
// 4 waves in 2x2; each wave 64x64 = 4x4 frags of 16x16x32.
// ---------------------------------------------------------------------------
static __device__ __forceinline__ void gemm_core_128(
    const ushort* __restrict__ A, const ushort* __restrict__ B, int lda,
    int ldb, int K, ushort* ldsA, ushort* ldsB, float4v acc[4][4]) {
  const int tid = threadIdx.x;
  const int l = tid & 63, w = tid >> 6;
  const int lane16 = l & 15, quad = l >> 4;
  const int wm = w & 1, wn = w >> 1;
  const int lrow = l >> 3;        // 0..7
  const int lcol = (l & 7) * 8;   // element offset within row
#pragma unroll
  for (int i = 0; i < 4; ++i)
#pragma unroll
    for (int j = 0; j < 4; ++j) acc[i][j] = (float4v)0.0f;
  for (int kc = 0; kc < K; kc += 64) {
    __syncthreads();  // previous iter's ds_reads done before overwrite
#pragma unroll
    for (int t = 0; t < 4; ++t) {
      int row = w * 32 + t * 8;  // wave-uniform base row; lane adds lrow
      gl_lds16(A + (size_t)(row + lrow) * lda + kc + lcol,
               &ldsA[row * 64]);
      gl_lds16(B + (size_t)(row + lrow) * ldb + kc + lcol,
               &ldsB[row * 64]);
    }
    __syncthreads();  // compiler drains vmcnt before barrier
#pragma unroll
    for (int kk = 0; kk < 64; kk += 32) {
      const int ko = kk + quad * 8;
      short8 a[4], b[4];
#pragma unroll
      for (int i = 0; i < 4; ++i)
        a[i] = *(const short8*)&ldsA[(wm * 64 + i * 16 + lane16) * 64 + ko];
#pragma unroll
      for (int j = 0; j < 4; ++j)
        b[j] = *(const short8*)&ldsB[(wn * 64 + j * 16 + lane16) * 64 + ko];
#pragma unroll
      for (int i = 0; i < 4; ++i)
#pragma unroll
        for (int j = 0; j < 4; ++j)
          acc[i][j] = __builtin_amdgcn_mfma_f32_16x16x32_bf16(
              a[i], b[j], acc[i][j], 0, 0, 0);
    }
  }
}

// ---------------------------------------------------------------------------
// Kernel 5: kv0[bn][d][e] = sum_s kT[n][d][s] * vT[bn][e][s]   (K=512)
// ---------------------------------------------------------------------------
__global__ __launch_bounds__(256) void k_gemm1(
    const ushort* __restrict__ kTb, const ushort* __restrict__ vTb,
    ushort* __restrict__ kv0) {
  __shared__ ushort ldsA[128 * 64], ldsB[128 * 64];
  const int bx = blockIdx.x, by = blockIdx.y, bz = blockIdx.z;
  const int n = bz % N_;
  float4v acc[4][4];
  gemm_core_128(kTb + ((size_t)n * D_ + bx * 128) * S_,
                vTb + ((size_t)bz * D_ + by * 128) * S_, S_, S_, S_, ldsA,
                ldsB, acc);
  const int l = threadIdx.x & 63, w = threadIdx.x >> 6;
  const int lane16 = l & 15, quad = l >> 4;
  const int wm = w & 1, wn = w >> 1;
  ushort* C = kv0 + (size_t)bz * D_ * D_;
#pragma unroll
  for (int i = 0; i < 4; ++i)
#pragma unroll
    for (int j = 0; j < 4; ++j)
#pragma unroll
      for (int r = 0; r < 4; ++r)
        C[(size_t)(bx * 128 + wm * 64 + i * 16 + quad * 4 + r) * D_ +
          by * 128 + wn * 64 + j * 16 + lane16] = f2bf(acc[i][j][r]);
}

// ---------------------------------------------------------------------------
// Kernel 6: kvWT[bn][c][d] = sum_e WvT[c][e] * kv0[bn][d][e]   (K=256)
// ---------------------------------------------------------------------------
__global__ __launch_bounds__(256) void k_gemm2(
    const ushort* __restrict__ WvT, const ushort* __restrict__ kv0,
    ushort* __restrict__ kvWT) {
  __shared__ ushort ldsA[128 * 64], ldsB[128 * 64];
  const int bx = blockIdx.x, by = blockIdx.y, bz = blockIdx.z;
  float4v acc[4][4];
  gemm_core_128(WvT + (size_t)(bx * 128) * D_,
                kv0 + (size_t)bz * D_ * D_ + (size_t)(by * 128) * D_, D_, D_,
                D_, ldsA, ldsB, acc);
  const int l = threadIdx.x & 63, w = threadIdx.x >> 6;
  const int lane16 = l & 15, quad = l >> 4;
  const int wm = w & 1, wn = w >> 1;
  ushort* C = kvWT + (size_t)bz * D_ * D_;
#pragma unroll
  for (int i = 0; i < 4; ++i)
#pragma unroll
    for (int j = 0; j < 4; ++j)
#pragma unroll
      for (int r = 0; r < 4; ++r)
        C[(size_t)(bx * 128 + wm * 64 + i * 16 + quad * 4 + r) * D_ +
          by * 128 + wn * 64 + j * 16 + lane16] = f2bf(acc[i][j][r]);
}

// ---------------------------------------------------------------------------
// Kernel 7: out[bn][s][c] = sum_d q[n][s][d] * kvWT[bn][c][d] + bv[c] (K=256)
// ---------------------------------------------------------------------------
__global__ __launch_bounds__(256) void k_gemm3(
    const ushort* __restrict__ qb, const ushort* __restrict__ kvWT,
    const float* __restrict__ bv, float* __restrict__ out) {
  __shared__ ushort ldsA[128 * 64], ldsB[128 * 64];
  const int bx = blockIdx.x, by = blockIdx.y, bz = blockIdx.z;
  const int n = bz % N_;
  float4v acc[4][4];
  gemm_core_128(qb + ((size_t)n * S_ + bx * 128) * D_,
                kvWT + (size_t)bz * D_ * D_ + (size_t)(by * 128) * D_, D_, D_,
                D_, ldsA, ldsB, acc);
  const int l = threadIdx.x & 63, w = threadIdx.x >> 6;
  const int lane16 = l & 15, quad = l >> 4;
  const int wm = w & 1, wn = w >> 1;
  float* C = out + (size_t)bz * S_ * D_;
#pragma unroll
  for (int j = 0; j < 4; ++j) {
    const int c = by * 128 + wn * 64 + j * 16 + lane16;
    const float bvc = bv[c];
#pragma unroll
    for (int i = 0; i < 4; ++i)
#pragma unroll
      for (int r = 0; r < 4; ++r)
        C[(size_t)(bx * 128 + wm * 64 + i * 16 + quad * 4 + r) * D_ + c] =
            acc[i][j][r] + bvc;
  }
}

// ---------------------------------------------------------------------------
extern "C" void kernel_launch(void* const* d_in, const int* in_sizes, int n_in,
                              void* d_out, int out_size, void* d_ws,
                              size_t ws_size, hipStream_t stream) {
  const float* value = (const float*)d_in[0];  // [B,N,S,D]
  const float* emb   = (const float*)d_in[1];  // [N,S,A]
  const float* Wqk   = (const float*)d_in[2];  // [A,D]
  const float* bqk   = (const float*)d_in[3];  // [D]
  const float* Wv    = (const float*)d_in[4];  // [D,D]
  const float* bv    = (const float*)d_in[5];  // [D]
  float* out = (float*)d_out;

  // ws layout (bytes), total ~204 MiB (ws is ~768 MiB per fill evidence):
  char* ws = (char*)d_ws;
  float*  qk   = (float*)ws;                     //  6,291,456
  ushort* qb   = (ushort*)(ws + 6291456);        //  3,145,728
  ushort* kTb  = (ushort*)(ws + 9437184);        //  3,145,728
  ushort* WvT  = (ushort*)(ws + 12582912);       //    131,072
  ushort* vTb  = (ushort*)(ws + 12713984);       // 100,663,296
  ushort* kv0  = (ushort*)(ws + 113377280);      //  50,331,648
  ushort* kvWT = (ushort*)(ws + 163708928);      //  50,331,648

  k_qk_softmax_q<<<dim3(N_ * S_), 256, 0, stream>>>(emb, Wqk, bqk, qk, qb);
  k_softmax_kT<<<dim3(D_, N_), 256, 0, stream>>>(qk, kTb);
  k_wvt<<<dim3(D_), 256, 0, stream>>>(Wv, WvT);
  k_vT<<<dim3(8, 4, B_ * N_), 256, 0, stream>>>(value, vTb);
  k_gemm1<<<dim3(2, 2, B_ * N_), 256, 0, stream>>>(kTb, vTb, kv0);
  k_gemm2<<<dim3(2, 2, B_ * N_), 256, 0, stream>>>(WvT, kv0, kvWT);
  k_gemm3<<<dim3(4, 2, B_ * N_), 256, 0, stream>>>(qb, kvWT, bv, out);
}